// Round 2
// baseline (358.471 us; speedup 1.0000x reference)
//
#include <hip/hip_runtime.h>

// LocalConnectivity: out[i][j] = sum_{1<=|dx|+|dy|<=5} w_{|dx|+|dy|} * s[(i+dx)&4095][(j+dy)&4095]
// w_d = exp(-d/2) = r^d  =>  separable per diagonal: w_{|dx|+|dy|} = r^|dx| * r^|dy|
// out[i][j] = sum_{dx=-5..5} r^|dx| * H_{5-|dx|}[i+dx][j] - s[i][j]
// H_k[t][j] = sum_{|dy|<=k} r^|dy| s[t][j+dy]  (incremental: 5 add + 5 fma)
//
// R8: XCD-band swizzle + NT stores cut hbm_bytes 262->104 MB (input is L3-resident,
// FETCH=33MB; WRITE=68MB = mandatory). BUT VGPR crept 128->136, crossing the
// gfx950 occupancy step at 128 -> waves/SIMD cap halved 4->2 (Occupancy 18.8->9.4),
// so the kernel went latency-bound at 1.8 TB/s.
// R9: force __launch_bounds__(256, 4) (min 4 waves/EU => VGPR <= 128) to restore
// the concurrency. Body unchanged (R7 compiled this loop at 128 VGPR, no spills).

#define GH     4096
#define GMASK  4095
#define RCHUNK 4           // output rows per thread
#define NR     (RCHUNK + 10)   // 14 input rows streamed

typedef float f4 __attribute__((ext_vector_type(4), aligned(16)));

__global__ __launch_bounds__(256, 4)   // cap VGPR at 128 -> 4 waves/SIMD
void diamond_stencil(const float* __restrict__ s, const float* __restrict__ w,
                     float* __restrict__ out)
{
    const int tid = threadIdx.x;

    // XCD-band swizzle: dispatch assigns consecutive blockIdx round-robin over
    // 8 XCDs. Map bid so XCD k gets y-chunks [k*128, (k+1)*128), both column
    // strips, consecutive idx -> neighboring y (halo sharers co-resident in L2).
    const int bid = blockIdx.x;            // 0..2047
    const int xcd = bid & 7;
    const int idx = bid >> 3;              // 0..255 within this XCD
    const int bx  = idx & 1;               // column strip
    const int by  = xcd * 128 + (idx >> 1);// y-chunk, contiguous band per XCD

    const int j0  = bx * 2048 + tid * 8;   // 8 columns per thread, 32B-aligned
    const int t0  = by * RCHUNK;           // 4 output rows per thread

    // wrapped column bases (all float4 bases stay 16B-aligned; wrap only at strip edges)
    const int cL  = (j0 - 5) & GMASK;      // scalar left halo
    const int cm4 = (j0 - 4) & GMASK;
    const int cp8 = (j0 + 8) & GMASK;
    const int cR  = (j0 + 12) & GMASK;     // scalar right halo

    float wgt[6];
    wgt[0] = 1.0f;
#pragma unroll
    for (int d = 1; d <= 5; ++d) wgt[d] = w[d - 1];   // exp(-d/2)

    float acc[RCHUNK][8];
#pragma unroll
    for (int a = 0; a < RCHUNK; ++a)
#pragma unroll
        for (int c = 0; c < 8; ++c) acc[a][c] = 0.0f;

#pragma unroll
    for (int r = 0; r < NR; ++r) {
        const float* row = s + ((size_t)((t0 - 5 + r) & GMASK) << 12);

        // 18 floats: cols j0-5 .. j0+12 (6 independent loads, hoistable)
        float v[18];
        v[0] = row[cL];
        const float4 A = *(const float4*)(row + cm4);
        const float4 B = *(const float4*)(row + j0);
        const float4 C = *(const float4*)(row + j0 + 4);
        const float4 D = *(const float4*)(row + cp8);
        v[17] = row[cR];
        v[1]  = A.x; v[2]  = A.y; v[3]  = A.z; v[4]  = A.w;
        v[5]  = B.x; v[6]  = B.y; v[7]  = B.z; v[8]  = B.w;
        v[9]  = C.x; v[10] = C.y; v[11] = C.z; v[12] = C.w;
        v[13] = D.x; v[14] = D.y; v[15] = D.z; v[16] = D.w;

#pragma unroll
        for (int c = 0; c < 8; ++c) {
            const float ctr = v[5 + c];
            float Hs[6];
            Hs[0] = ctr;
#pragma unroll
            for (int k = 1; k <= 5; ++k)
                Hs[k] = Hs[k - 1] + wgt[k] * (v[5 + c - k] + v[5 + c + k]);

            // input row t = t0-5+r contributes to output row o = t0+a iff |r-5-a| <= 5
#pragma unroll
            for (int a = 0; a < RCHUNK; ++a) {
                const int d = r - 5 - a;               // compile-time
                if (d < -5 || d > 5) continue;
                if (d == 0)
                    acc[a][c] += Hs[5] - ctr;          // center excluded
                else {
                    const int ad = d < 0 ? -d : d;
                    acc[a][c] += wgt[ad] * Hs[5 - ad];
                }
            }
        }
    }

    // store 4 rows x 8 cols, nontemporal (evict-first: don't thrash L2 read set)
#pragma unroll
    for (int a = 0; a < RCHUNK; ++a) {
        float* op = out + ((size_t)(t0 + a) << 12) + j0;
        f4 r0, r1;
        r0.x = acc[a][0]; r0.y = acc[a][1]; r0.z = acc[a][2]; r0.w = acc[a][3];
        r1.x = acc[a][4]; r1.y = acc[a][5]; r1.z = acc[a][6]; r1.w = acc[a][7];
        __builtin_nontemporal_store(r0, (f4*)op);
        __builtin_nontemporal_store(r1, (f4*)(op + 4));
    }
}

extern "C" void kernel_launch(void* const* d_in, const int* in_sizes, int n_in,
                              void* d_out, int out_size, void* d_ws, size_t ws_size,
                              hipStream_t stream)
{
    const float* s = (const float*)d_in[0];   // grid_spikes [4096*4096] f32
    const float* w = (const float*)d_in[1];   // distance_weights [5] f32
    float* out = (float*)d_out;               // [4096*4096] f32

    // 2048 blocks (2 col strips x 1024 row-chunks), XCD-band swizzled in-kernel
    dim3 grid(2048);
    dim3 block(256);
    diamond_stencil<<<grid, block, 0, stream>>>(s, w, out);
}

// Round 3
// 135.831 us; speedup vs baseline: 2.6391x; 2.6391x over previous
//
#include <hip/hip_runtime.h>

// LocalConnectivity: out[i][j] = sum_{1<=|dx|+|dy|<=5} w_{|dx|+|dy|} * s[(i+dx)&4095][(j+dy)&4095]
// w_d = exp(-d/2) = r^d  =>  separable per diagonal: w_{|dx|+|dy|} = r^|dx| * r^|dy|
// out[i][j] = sum_{dx=-5..5} r^|dx| * H_{5-|dx|}[i+dx][j] - s[i][j]
// H_k[t][j] = sum_{|dy|<=k} r^|dy| s[t][j+dy]  (incremental: 5 add + 5 fma)
//
// R8: XCD-band swizzle + NT stores: hbm_bytes 262->104 MB (FETCH=33, WRITE=68=mandatory)
//     but VGPR 128->136 crossed the occupancy step (3 waves/SIMD not 4) -> 54 us.
// R9: __launch_bounds__(256,4) FAILED: allocator jumped to VGPR=64 + ~550 MB of
//     scratch spills each way (FETCH 495 MB / WRITE 618 MB), 293 us. Min-waves
//     bounds are a blunt instrument on gfx950 -- never again on this kernel.
// R10: shave the 8-VGPR overshoot at source instead: pin the 5 wave-uniform
//     distance weights in SGPRs via readfirstlane (VALU reads 1 SGPR operand
//     free), no launch bound. Target VGPR <= 128 -> 4 waves/SIMD restored.

#define GH     4096
#define GMASK  4095
#define RCHUNK 4           // output rows per thread
#define NR     (RCHUNK + 10)   // 14 input rows streamed

typedef float f4 __attribute__((ext_vector_type(4), aligned(16)));

__device__ __forceinline__ float uniform_f(float x) {
    union { float f; int i; } u;
    u.f = x;
    u.i = __builtin_amdgcn_readfirstlane(u.i);   // pin in SGPR (wave-uniform)
    return u.f;
}

__global__ __launch_bounds__(256)
void diamond_stencil(const float* __restrict__ s, const float* __restrict__ w,
                     float* __restrict__ out)
{
    const int tid = threadIdx.x;

    // XCD-band swizzle: dispatch assigns consecutive blockIdx round-robin over
    // 8 XCDs. Map bid so XCD k gets y-chunks [k*128, (k+1)*128), both column
    // strips, consecutive idx -> neighboring y (halo sharers co-resident in L2).
    const int bid = blockIdx.x;            // 0..2047
    const int xcd = bid & 7;
    const int idx = bid >> 3;              // 0..255 within this XCD
    const int bx  = idx & 1;               // column strip
    const int by  = xcd * 128 + (idx >> 1);// y-chunk, contiguous band per XCD

    const int j0  = bx * 2048 + tid * 8;   // 8 columns per thread, 32B-aligned
    const int t0  = by * RCHUNK;           // 4 output rows per thread

    // wrapped column bases (all float4 bases stay 16B-aligned; wrap only at strip edges)
    const int cL  = (j0 - 5) & GMASK;      // scalar left halo
    const int cm4 = (j0 - 4) & GMASK;
    const int cp8 = (j0 + 8) & GMASK;
    const int cR  = (j0 + 12) & GMASK;     // scalar right halo

    // weights in SGPRs: wave-uniform, saves ~6 VGPRs vs vector copies
    float wgt[6];
    wgt[0] = 1.0f;
#pragma unroll
    for (int d = 1; d <= 5; ++d) wgt[d] = uniform_f(w[d - 1]);   // exp(-d/2)

    float acc[RCHUNK][8];
#pragma unroll
    for (int a = 0; a < RCHUNK; ++a)
#pragma unroll
        for (int c = 0; c < 8; ++c) acc[a][c] = 0.0f;

#pragma unroll
    for (int r = 0; r < NR; ++r) {
        const float* row = s + ((size_t)((t0 - 5 + r) & GMASK) << 12);

        // 18 floats: cols j0-5 .. j0+12 (6 independent loads, hoistable)
        float v[18];
        v[0] = row[cL];
        const float4 A = *(const float4*)(row + cm4);
        const float4 B = *(const float4*)(row + j0);
        const float4 C = *(const float4*)(row + j0 + 4);
        const float4 D = *(const float4*)(row + cp8);
        v[17] = row[cR];
        v[1]  = A.x; v[2]  = A.y; v[3]  = A.z; v[4]  = A.w;
        v[5]  = B.x; v[6]  = B.y; v[7]  = B.z; v[8]  = B.w;
        v[9]  = C.x; v[10] = C.y; v[11] = C.z; v[12] = C.w;
        v[13] = D.x; v[14] = D.y; v[15] = D.z; v[16] = D.w;

#pragma unroll
        for (int c = 0; c < 8; ++c) {
            const float ctr = v[5 + c];
            float Hs[6];
            Hs[0] = ctr;
#pragma unroll
            for (int k = 1; k <= 5; ++k)
                Hs[k] = Hs[k - 1] + wgt[k] * (v[5 + c - k] + v[5 + c + k]);

            // input row t = t0-5+r contributes to output row o = t0+a iff |r-5-a| <= 5
#pragma unroll
            for (int a = 0; a < RCHUNK; ++a) {
                const int d = r - 5 - a;               // compile-time
                if (d < -5 || d > 5) continue;
                if (d == 0)
                    acc[a][c] += Hs[5] - ctr;          // center excluded
                else {
                    const int ad = d < 0 ? -d : d;
                    acc[a][c] += wgt[ad] * Hs[5 - ad];
                }
            }
        }
    }

    // store 4 rows x 8 cols, nontemporal (evict-first: don't thrash L2 read set)
#pragma unroll
    for (int a = 0; a < RCHUNK; ++a) {
        float* op = out + ((size_t)(t0 + a) << 12) + j0;
        f4 r0, r1;
        r0.x = acc[a][0]; r0.y = acc[a][1]; r0.z = acc[a][2]; r0.w = acc[a][3];
        r1.x = acc[a][4]; r1.y = acc[a][5]; r1.z = acc[a][6]; r1.w = acc[a][7];
        __builtin_nontemporal_store(r0, (f4*)op);
        __builtin_nontemporal_store(r1, (f4*)(op + 4));
    }
}

extern "C" void kernel_launch(void* const* d_in, const int* in_sizes, int n_in,
                              void* d_out, int out_size, void* d_ws, size_t ws_size,
                              hipStream_t stream)
{
    const float* s = (const float*)d_in[0];   // grid_spikes [4096*4096] f32
    const float* w = (const float*)d_in[1];   // distance_weights [5] f32
    float* out = (float*)d_out;               // [4096*4096] f32

    // 2048 blocks (2 col strips x 1024 row-chunks), XCD-band swizzled in-kernel
    dim3 grid(2048);
    dim3 block(256);
    diamond_stencil<<<grid, block, 0, stream>>>(s, w, out);
}

// Round 5
// 125.705 us; speedup vs baseline: 2.8517x; 1.0806x over previous
//
#include <hip/hip_runtime.h>

// LocalConnectivity: out[i][j] = sum_{1<=|dx|+|dy|<=5} w_{|dx|+|dy|} * s[(i+dx)&4095][(j+dy)&4095]
// w_d = exp(-d/2) = r^d  =>  separable per diagonal: w_{|dx|+|dy|} = r^|dx| * r^|dy|
// out[i][j] = sum_{dx=-5..5} r^|dx| * H_{5-|dx|}[i+dx][j] - s[i][j]
// H_k[t][j] = sum_{|dy|<=k} r^|dy| s[t][j+dy]  (incremental: 5 add + 5 fma)
//
// R8:  XCD-band swizzle + NT stores: hbm_bytes 262->104 MB (FETCH=33 = L3-resident
//      input, WRITE=68 = mandatory). But VGPR 128->136 crossed the occupancy step
//      (4->3 waves/SIMD, occ 18.9->9%) -> BW collapsed 3.8->1.9 TB/s, 54 us.
// R9:  __launch_bounds__(256,4) FAILED: allocator went to VGPR=64 + 550 MB spills.
// R10: readfirstlane weight pin FAILED to move VGPR (still 136) -- edge shaving
//      doesn't fix a structural 8-reg overshoot.
// R11: shrink the structural arrays: COLS 8->4 (acc 32->16 VGPRs, v 18->14).
//      Same arithmetic per output (35+11 ops); grid doubles to 4096 blocks (2x TLP).
//      Target VGPR <= 112 -> 4+ waves/SIMD, restoring R7's 3.8+ TB/s on R8's 104 MB.
// R12: R11 bench was an infra failure (container acquire), not a kernel fault
//      (audited: no OOB, no sync, no races). Resubmitting R11 unchanged.

#define GH     4096
#define GMASK  4095
#define RCHUNK 4            // output rows per thread
#define COLS   4            // output cols per thread
#define NR     (RCHUNK + 10)   // 14 input rows streamed

typedef float f4 __attribute__((ext_vector_type(4), aligned(16)));

__device__ __forceinline__ float uniform_f(float x) {
    union { float f; int i; } u;
    u.f = x;
    u.i = __builtin_amdgcn_readfirstlane(u.i);   // pin in SGPR (wave-uniform)
    return u.f;
}

__global__ __launch_bounds__(256)
void diamond_stencil(const float* __restrict__ s, const float* __restrict__ w,
                     float* __restrict__ out)
{
    const int tid = threadIdx.x;

    // XCD-band swizzle: consecutive blockIdx round-robins over 8 XCDs.
    // XCD k owns y-chunks [k*128,(k+1)*128); within a band, the 4 column strips
    // of one y-chunk are consecutive (strip fastest) so halo-sharing neighbors
    // are co-resident in the same 4 MiB L2 (~2.5 MB window).
    const int bid = blockIdx.x;              // 0..4095
    const int xcd = bid & 7;
    const int idx = bid >> 3;                // 0..511 within this XCD
    const int bx  = idx & 3;                 // column strip (1024 cols each)
    const int by  = xcd * 128 + (idx >> 2);  // y-chunk, contiguous band per XCD

    const int j0  = bx * 1024 + tid * COLS;  // 4 cols per thread, 16B-aligned
    const int t0  = by * RCHUNK;             // 4 output rows per thread

    // wrapped column bases (vec4 bases stay 16B-aligned; wrap only at grid edge)
    const int cL  = (j0 - 5) & GMASK;        // scalar left halo
    const int cm4 = (j0 - 4) & GMASK;
    const int cp4 = (j0 + 4) & GMASK;
    const int cR  = (j0 + 8) & GMASK;        // scalar right halo

    float wgt[6];
    wgt[0] = 1.0f;
#pragma unroll
    for (int d = 1; d <= 5; ++d) wgt[d] = uniform_f(w[d - 1]);   // exp(-d/2)

    float acc[RCHUNK][COLS];
#pragma unroll
    for (int a = 0; a < RCHUNK; ++a)
#pragma unroll
        for (int c = 0; c < COLS; ++c) acc[a][c] = 0.0f;

#pragma unroll
    for (int r = 0; r < NR; ++r) {
        const float* row = s + ((size_t)((t0 - 5 + r) & GMASK) << 12);

        // 14 floats: cols j0-5 .. j0+8 (5 independent loads, hoistable)
        float v[14];
        v[0] = row[cL];
        const float4 A = *(const float4*)(row + cm4);
        const float4 B = *(const float4*)(row + j0);
        const float4 C = *(const float4*)(row + cp4);
        v[13] = row[cR];
        v[1]  = A.x; v[2]  = A.y; v[3]  = A.z; v[4]  = A.w;
        v[5]  = B.x; v[6]  = B.y; v[7]  = B.z; v[8]  = B.w;
        v[9]  = C.x; v[10] = C.y; v[11] = C.z; v[12] = C.w;

#pragma unroll
        for (int c = 0; c < COLS; ++c) {
            const float ctr = v[5 + c];
            float Hs[6];
            Hs[0] = ctr;
#pragma unroll
            for (int k = 1; k <= 5; ++k)
                Hs[k] = Hs[k - 1] + wgt[k] * (v[5 + c - k] + v[5 + c + k]);

            // input row t = t0-5+r contributes to output row o = t0+a iff |r-5-a| <= 5
#pragma unroll
            for (int a = 0; a < RCHUNK; ++a) {
                const int d = r - 5 - a;               // compile-time
                if (d < -5 || d > 5) continue;
                if (d == 0)
                    acc[a][c] += Hs[5] - ctr;          // center excluded
                else {
                    const int ad = d < 0 ? -d : d;
                    acc[a][c] += wgt[ad] * Hs[5 - ad];
                }
            }
        }
    }

    // store 4 rows x 4 cols, nontemporal (evict-first: don't thrash L2 read set)
#pragma unroll
    for (int a = 0; a < RCHUNK; ++a) {
        float* op = out + ((size_t)(t0 + a) << 12) + j0;
        f4 r0;
        r0.x = acc[a][0]; r0.y = acc[a][1]; r0.z = acc[a][2]; r0.w = acc[a][3];
        __builtin_nontemporal_store(r0, (f4*)op);
    }
}

extern "C" void kernel_launch(void* const* d_in, const int* in_sizes, int n_in,
                              void* d_out, int out_size, void* d_ws, size_t ws_size,
                              hipStream_t stream)
{
    const float* s = (const float*)d_in[0];   // grid_spikes [4096*4096] f32
    const float* w = (const float*)d_in[1];   // distance_weights [5] f32
    float* out = (float*)d_out;               // [4096*4096] f32

    // 4096 blocks (4 col strips x 1024 row-chunks), XCD-band swizzled in-kernel
    dim3 grid(4096);
    dim3 block(256);
    diamond_stencil<<<grid, block, 0, stream>>>(s, w, out);
}

// Round 6
// 123.789 us; speedup vs baseline: 2.8958x; 1.0155x over previous
//
#include <hip/hip_runtime.h>
#include <stdint.h>

// LocalConnectivity: out[i][j] = sum_{1<=|dx|+|dy|<=5} w_{|dx|+|dy|} * s[(i+dx)&4095][(j+dy)&4095]
// Separable: out[i][j] = sum_{dx=-5..5} r^|dx| * H_{5-|dx|}[i+dx][j] - s[i][j],
//   H_k[t][j] = sum_{|dy|<=k} r^|dy| s[t][j+dy]
//
// R12 result: traffic minimal (steady FETCH~0 = input L3-resident, WRITE=65MB),
// occ 25%, VGPR 80 -- yet dur stuck at 57us, BW 1.2 TB/s, VALUBusy 17%.
// Diagnosis: 14 serial load->vmcnt(0)->compute round-trips per wave; compiler
// won't pipeline rows in registers (R7 session hit same wall). Latency chain,
// ~4000cy exposed per row under queueing.
// R13: async LDS staging. Block = 1024 cols x 8 rows; stage all 18 input rows
// (74.9 KB LDS) via global_load_lds (all in flight at once), ONE sync, compute
// from LDS with aligned ds_read_b128. Exposed latency: 14xL/wave -> ~1xL/block,
// hidden by the co-resident block (2 blocks/CU, LDS-capped -> VGPR cliff moot).

#define GMASK  4095
#define TR     8               // output rows per block
#define NRW    (TR + 10)       // 18 staged input rows
#define LW     1040            // LDS row: 8 pad | 1024 | 8 pad  (floats)

typedef float f4 __attribute__((ext_vector_type(4), aligned(16)));

#define GLOBAL_AS __attribute__((address_space(1)))
#define LDS_AS    __attribute__((address_space(3)))

__device__ __forceinline__ void stage16(const float* g, float* l) {
    // lane i of the wave loads 16B from (g + i*4 floats) into ldsbase + i*16B
    __builtin_amdgcn_global_load_lds((const GLOBAL_AS uint32_t*)g,
                                     (LDS_AS uint32_t*)l, 16, 0, 0);
}

__device__ __forceinline__ float uniform_f(float x) {
    union { float f; int i; } u;
    u.f = x;
    u.i = __builtin_amdgcn_readfirstlane(u.i);
    return u.f;
}

__global__ __launch_bounds__(256)
void diamond_stencil(const float* __restrict__ s, const float* __restrict__ w,
                     float* __restrict__ out)
{
    __shared__ float tile[NRW][LW];          // 18*1040*4 = 74880 B

    const int tid  = threadIdx.x;
    const int lane = tid & 63;
    const int wv   = tid >> 6;               // wave 0..3

    // XCD band swizzle: 2048 blocks, xcd k owns y-chunks [k*64,(k+1)*64),
    // strips fastest -> halo-sharing neighbors co-resident in one L2.
    const int bid = blockIdx.x;              // 0..2047
    const int xcd = bid & 7;
    const int idx = bid >> 3;                // 0..255
    const int bx  = idx & 3;                 // column strip (1024 cols)
    const int by  = xcd * 64 + (idx >> 2);   // y-chunk 0..511

    const int j0 = bx << 10;                 // strip base col (multiple of 1024)
    const int t0 = by * TR;                  // first output row

    // ---- async stage: main 1024 floats/row; wave wv does rows wv, wv+4, ... ----
    for (int r = wv; r < NRW; r += 4) {
        const float* srow = s + ((size_t)((t0 - 5 + r) & GMASK) << 12);
        float* lrow = &tile[r][8];
#pragma unroll
        for (int q = 0; q < 4; ++q)          // 4 x (64 lanes x 16B) = 4 KB row
            stage16(srow + j0 + q * 256 + lane * 4, lrow + q * 256);
    }

    // ---- halo: 18 rows x {8 left, 8 right} floats = 72 x 16B chunks ----
    if (tid < NRW * 4) {
        const int r  = tid >> 2, p = tid & 3;
        const int gc = (p < 2 ? j0 - 8 + p * 4 : j0 + 1024 + (p - 2) * 4) & GMASK;
        const int lc = (p < 2 ? p * 4 : 1032 + (p - 2) * 4);
        const float* srow = s + ((size_t)((t0 - 5 + r) & GMASK) << 12);
        *(f4*)&tile[r][lc] = *(const f4*)(srow + gc);   // 16B aligned both sides
    }

    __syncthreads();   // drains vmcnt (global_load_lds) + lgkm (halo ds_write)

    float wgt[6];
    wgt[0] = 1.0f;
#pragma unroll
    for (int d = 1; d <= 5; ++d) wgt[d] = uniform_f(w[d - 1]);   // exp(-d/2)

    float acc[TR][4];
#pragma unroll
    for (int a = 0; a < TR; ++a)
#pragma unroll
        for (int c = 0; c < 4; ++c) acc[a][c] = 0.0f;

    const int tc = tid * 4;                  // this thread's padded col base

#pragma unroll
    for (int r = 0; r < NRW; ++r) {
        // aligned 20-float window: padded cols tc .. tc+19 (need tc+3 .. tc+16)
        const f4* lp = (const f4*)&tile[r][tc];   // (r*1040 + tc)*4 is 16B-aligned
        const f4 A = lp[0], B = lp[1], C = lp[2], D = lp[3], E = lp[4];
        float f[20];
        f[0]=A.x; f[1]=A.y; f[2]=A.z; f[3]=A.w;
        f[4]=B.x; f[5]=B.y; f[6]=B.z; f[7]=B.w;
        f[8]=C.x; f[9]=C.y; f[10]=C.z; f[11]=C.w;
        f[12]=D.x; f[13]=D.y; f[14]=D.z; f[15]=D.w;
        f[16]=E.x; f[17]=E.y; f[18]=E.z; f[19]=E.w;

#pragma unroll
        for (int c = 0; c < 4; ++c) {
            const float ctr = f[8 + c];      // padded col tc+8+c = real col tc+c
            float Hs[6];
            Hs[0] = ctr;
#pragma unroll
            for (int k = 1; k <= 5; ++k)
                Hs[k] = Hs[k - 1] + wgt[k] * (f[8 + c - k] + f[8 + c + k]);

            // input row t = t0-5+r feeds output row o = t0+a iff |r-5-a| <= 5
#pragma unroll
            for (int a = 0; a < TR; ++a) {
                const int d = r - 5 - a;     // compile-time
                if (d < -5 || d > 5) continue;
                if (d == 0)
                    acc[a][c] += Hs[5] - ctr;          // center excluded
                else {
                    const int ad = d < 0 ? -d : d;
                    acc[a][c] += wgt[ad] * Hs[5 - ad];
                }
            }
        }
    }

    // store 8 rows x 4 cols, nontemporal (don't thrash L2/L3 read set)
#pragma unroll
    for (int a = 0; a < TR; ++a) {
        float* op = out + ((size_t)(t0 + a) << 12) + j0 + tc;
        f4 r0;
        r0.x = acc[a][0]; r0.y = acc[a][1]; r0.z = acc[a][2]; r0.w = acc[a][3];
        __builtin_nontemporal_store(r0, (f4*)op);
    }
}

extern "C" void kernel_launch(void* const* d_in, const int* in_sizes, int n_in,
                              void* d_out, int out_size, void* d_ws, size_t ws_size,
                              hipStream_t stream)
{
    const float* s = (const float*)d_in[0];   // grid_spikes [4096*4096] f32
    const float* w = (const float*)d_in[1];   // distance_weights [5] f32
    float* out = (float*)d_out;               // [4096*4096] f32

    // 2048 blocks = 4 col strips x 512 row-chunks, XCD-band swizzled in-kernel
    dim3 grid(2048);
    dim3 block(256);
    diamond_stencil<<<grid, block, 0, stream>>>(s, w, out);
}

// Round 7
// 121.562 us; speedup vs baseline: 2.9489x; 1.0183x over previous
//
#include <hip/hip_runtime.h>
#include <stdint.h>

// LocalConnectivity: out[i][j] = sum_{1<=|dx|+|dy|<=5} w_{|dx|+|dy|} * s[(i+dx)&4095][(j+dy)&4095]
// Separable: out[i][j] = sum_{dx=-5..5} r^|dx| * H_{5-|dx|}[i+dx][j] - s[i][j],
//   H_k[t][j] = sum_{|dy|<=k} r^|dy| s[t][j+dy]
//
// R13: async LDS staging (1024x8 tile, 75KB) broke the per-wave latency chain:
//      57->43.5us, VALUBusy 22%. But 75KB LDS -> only 2 blocks/CU, so the
//      stage->vmcnt(0)->compute serialization is barely hidden (occ 9.3).
// R14: same pipeline, 4x more of them. 512-col strip, TR=8, 128 threads,
//      LDS=18*528*4=38KB -> 4 blocks/CU. Per-thread layout identical
//      (4 cols x 8 rows, aligned b128 20-float windows) so VALU/LDS totals
//      unchanged; 4 independent stage/compute pipelines per CU hide the drain.
//      Floors: VALU ~10us, LDS-read ~9.6us, NT-write ~10.4us -> target 24-30us.

#define GMASK  4095
#define TR     8               // output rows per block
#define NRW    (TR + 10)       // 18 staged input rows
#define SW     512             // strip width (cols per block)
#define LW     (SW + 16)       // LDS row: 8 pad | 512 | 8 pad = 528 floats

typedef float f4 __attribute__((ext_vector_type(4), aligned(16)));

#define GLOBAL_AS __attribute__((address_space(1)))
#define LDS_AS    __attribute__((address_space(3)))

__device__ __forceinline__ void stage16(const float* g, float* l) {
    // wave-collective: lane i loads 16B from (g + i*4 floats) into l + i*16B
    __builtin_amdgcn_global_load_lds((const GLOBAL_AS uint32_t*)g,
                                     (LDS_AS uint32_t*)l, 16, 0, 0);
}

__device__ __forceinline__ float uniform_f(float x) {
    union { float f; int i; } u;
    u.f = x;
    u.i = __builtin_amdgcn_readfirstlane(u.i);
    return u.f;
}

__global__ __launch_bounds__(128)
void diamond_stencil(const float* __restrict__ s, const float* __restrict__ w,
                     float* __restrict__ out)
{
    __shared__ float tile[NRW][LW];          // 18*528*4 = 38016 B -> 4 blocks/CU

    const int tid  = threadIdx.x;            // 0..127 (2 waves)
    const int lane = tid & 63;
    const int wv   = tid >> 6;               // wave 0..1

    // XCD band swizzle: 4096 blocks round-robin over 8 XCDs. XCD k owns the
    // 512-row band [k*512,(k+1)*512); within it, strips iterate fastest so
    // halo-sharing neighbors (left/right strips, same rows) are co-resident.
    const int bid = blockIdx.x;              // 0..4095
    const int xcd = bid & 7;
    const int i   = bid >> 3;                // 0..511 within this XCD
    const int bx  = i & 7;                   // strip (512 cols each)
    const int ys  = i >> 3;                  // 0..63 y-subband

    const int j0 = bx << 9;                  // strip base col
    const int t0 = xcd * 512 + ys * TR;      // first output row

    // ---- async stage: 18 rows x 512 floats; wave wv does rows wv, wv+2, ... ----
#pragma unroll
    for (int m = 0; m < 9; ++m) {
        const int r = wv + 2 * m;
        const float* srow = s + ((size_t)((t0 - 5 + r) & GMASK) << 12);
        float* lrow = &tile[r][8];
        stage16(srow + j0 + lane * 4,       lrow);
        stage16(srow + j0 + 256 + lane * 4, lrow + 256);
    }

    // ---- halo: 18 rows x {8 left, 8 right} floats = 72 x 16B chunks ----
    if (tid < NRW * 4) {
        const int r  = tid >> 2, p = tid & 3;
        const int gc = (p < 2 ? j0 - 8 + p * 4 : j0 + SW + (p - 2) * 4) & GMASK;
        const int lc = (p < 2 ? p * 4 : 8 + SW + (p - 2) * 4);
        const float* srow = s + ((size_t)((t0 - 5 + r) & GMASK) << 12);
        *(f4*)&tile[r][lc] = *(const f4*)(srow + gc);   // 16B aligned both sides
    }

    __syncthreads();   // drains vmcnt (global_load_lds) + lgkm (halo ds_write)

    float wgt[6];
    wgt[0] = 1.0f;
#pragma unroll
    for (int d = 1; d <= 5; ++d) wgt[d] = uniform_f(w[d - 1]);   // exp(-d/2)

    float acc[TR][4];
#pragma unroll
    for (int a = 0; a < TR; ++a)
#pragma unroll
        for (int c = 0; c < 4; ++c) acc[a][c] = 0.0f;

    const int tc = tid * 4;                  // thread's padded col base (16B-aligned)

#pragma unroll
    for (int r = 0; r < NRW; ++r) {
        // aligned 20-float window: padded cols tc .. tc+19 (need tc+3 .. tc+16)
        const f4* lp = (const f4*)&tile[r][tc];   // (r*528 + tc)*4 is 16B-aligned
        const f4 A = lp[0], B = lp[1], C = lp[2], D = lp[3], E = lp[4];
        float f[20];
        f[0]=A.x; f[1]=A.y; f[2]=A.z; f[3]=A.w;
        f[4]=B.x; f[5]=B.y; f[6]=B.z; f[7]=B.w;
        f[8]=C.x; f[9]=C.y; f[10]=C.z; f[11]=C.w;
        f[12]=D.x; f[13]=D.y; f[14]=D.z; f[15]=D.w;
        f[16]=E.x; f[17]=E.y; f[18]=E.z; f[19]=E.w;

#pragma unroll
        for (int c = 0; c < 4; ++c) {
            const float ctr = f[8 + c];      // padded col tc+8+c = real col j0+tc+c
            float Hs[6];
            Hs[0] = ctr;
#pragma unroll
            for (int k = 1; k <= 5; ++k)
                Hs[k] = Hs[k - 1] + wgt[k] * (f[8 + c - k] + f[8 + c + k]);

            // input row t = t0-5+r feeds output row o = t0+a iff |r-5-a| <= 5
#pragma unroll
            for (int a = 0; a < TR; ++a) {
                const int d = r - 5 - a;     // compile-time
                if (d < -5 || d > 5) continue;
                if (d == 0)
                    acc[a][c] += Hs[5] - ctr;          // center excluded
                else {
                    const int ad = d < 0 ? -d : d;
                    acc[a][c] += wgt[ad] * Hs[5 - ad];
                }
            }
        }
    }

    // store 8 rows x 4 cols, nontemporal (don't thrash L2/L3 read set)
#pragma unroll
    for (int a = 0; a < TR; ++a) {
        float* op = out + ((size_t)(t0 + a) << 12) + j0 + tc;
        f4 r0;
        r0.x = acc[a][0]; r0.y = acc[a][1]; r0.z = acc[a][2]; r0.w = acc[a][3];
        __builtin_nontemporal_store(r0, (f4*)op);
    }
}

extern "C" void kernel_launch(void* const* d_in, const int* in_sizes, int n_in,
                              void* d_out, int out_size, void* d_ws, size_t ws_size,
                              hipStream_t stream)
{
    const float* s = (const float*)d_in[0];   // grid_spikes [4096*4096] f32
    const float* w = (const float*)d_in[1];   // distance_weights [5] f32
    float* out = (float*)d_out;               // [4096*4096] f32

    // 4096 blocks = 8 col strips x 512 row-chunks, XCD-band swizzled in-kernel
    dim3 grid(4096);
    dim3 block(128);
    diamond_stencil<<<grid, block, 0, stream>>>(s, w, out);
}